// Round 8
// baseline (45.796 us; speedup 1.0000x reference)
//
#include <hip/hip_runtime.h>
#include <hip/hip_bf16.h>

// VQ-VAE quantize: x[32,64,64,64] NCHW fp32, codebook[512,64] fp32.
// out[0] = 1.25*SSD/8388608 ; out[1..] = codebook[argmin] in NCHW.
// R8: BARRIER-FREE wave pipeline. Each wave owns 32 rows end-to-end with
// wave-private LDS (x-area / store overlay / idx strip) -> zero __syncthreads,
// waves drift freely so x-read (HBM), B-scan (L2), store (HBM) overlap
// chip-wide. hn2 read per-ct from L1-hot global. nt hints on streaming I/O.
// Keys: u32 argmax key = (bits(score+1) & ~511) | (511-nc). Loss fused:
// SSD = sum(x^2) - 2*sum(best score), score = dot + 1 - ||c||^2/2.

typedef __attribute__((ext_vector_type(8))) __bf16 bf16x8;
typedef __attribute__((ext_vector_type(4))) float f32x4;

// ---- d_ws layout (bytes) ----
#define WS_CBF   0        // 65536: bf16 codebook B-fragments (32 ct x 2 kk x 1KB)
#define WS_HN2   65536    // 2048:  (1.0 - 0.5*||c||^2) f32[512]
#define WS_RED   67584    // 16384: per-wave loss partials f32[4096]

// ---- main kernel LDS (bytes) ----
// per-wave region: 9216 B = overlay f32[64 d][36 rows]; x-area = first 4096 B
#define WREG   9216
#define K_IDX  18432    // 2 waves x 32 ints = 256 B
#define K_SZ   18688

__device__ __forceinline__ unsigned f2b1(float f) {
  unsigned u = __float_as_uint(f);
  return (u + 0x7FFFu + ((u >> 16) & 1)) >> 16;   // RNE float->bf16 bits
}
__device__ __forceinline__ unsigned pack2(float lo, float hi) {
  return f2b1(lo) | (f2b1(hi) << 16);
}
#if defined(__has_builtin)
#  if __has_builtin(__builtin_amdgcn_perm)
#    define PACKTR(lo, hi) __builtin_amdgcn_perm(__float_as_uint(hi), \
                             __float_as_uint(lo), 0x07060302u)
#  endif
#endif
#ifndef PACKTR   // fallback: 2-op truncation pack
#  define PACKTR(lo, hi) ((__float_as_uint(hi) & 0xFFFF0000u) | \
                          (__float_as_uint(lo) >> 16))
#endif
__device__ __forceinline__ int swz(int row) {    // XOR swizzle, 16B granules
  return ((row & 7) ^ ((row >> 4) & 7)) << 4;
}

// ================= k0: codebook -> fragment layout + hn2 =================
__global__ void vq_prep(const float* __restrict__ cb, char* __restrict__ ws) {
  const int n = blockIdx.x * 64 + threadIdx.x;    // code 0..511
  const float4* cb4 = (const float4*)cb;
  float4 f[16];
  #pragma unroll
  for (int j = 0; j < 16; ++j) f[j] = cb4[(n << 4) + j];
  float s = 0.f;
  #pragma unroll
  for (int j = 0; j < 16; ++j)
    s += f[j].x * f[j].x + f[j].y * f[j].y + f[j].z * f[j].z + f[j].w * f[j].w;
  ((float*)(ws + WS_HN2))[n] = 1.0f - 0.5f * s;   // +1 shift keeps scores >0
  const int ct = n >> 4, col = n & 15;
  // B-fragment: lane = (g<<4)|col holds code ct*16+col, k = kk*32+g*8+e
  #pragma unroll
  for (int kk = 0; kk < 2; ++kk) {
    #pragma unroll
    for (int g = 0; g < 4; ++g) {
      float4 a = f[kk * 8 + g * 2], b = f[kk * 8 + g * 2 + 1];
      uint4 u = {pack2(a.x, a.y), pack2(a.z, a.w), pack2(b.x, b.y), pack2(b.z, b.w)};
      *(uint4*)(ws + WS_CBF + (((ct << 1) + kk) << 10) + (((g << 4) | col) << 4)) = u;
    }
  }
}

// ================= k1: argmin + loss + scatter (barrier-free) =================
__global__ void __launch_bounds__(128, 4)
vq_main(const float* __restrict__ x, const float* __restrict__ cb,
        const char* __restrict__ wsr, float* __restrict__ out,
        float* __restrict__ wsw) {
  __shared__ __align__(16) char smem[K_SZ];
  const int t    = threadIdx.x;           // 0..127
  const int lane = t & 63;
  const int wid  = t >> 6;                // wave in block
  const int bid  = blockIdx.x;            // 0..2047
  const int bimg = bid >> 6;
  const int wrow0 = ((bid & 63) << 6) + (wid << 5);   // wave's 32-row base

  char*  xw   = smem + wid * WREG;                    // bf16 [32][64] swizzled
  float* ovl  = (float*)(smem + wid * WREG);          // overlay f32 [64][36]
  int*   idxw = (int*)(smem + K_IDX) + (wid << 5);    // wave-private idx[32]

  const f32x4*  xb4  = (const f32x4*)(x + (bimg << 18) + wrow0);
  const float4* cb4  = (const float4*)cb;
  const bf16x8* cbb  = (const bf16x8*)(wsr + WS_CBF); // fragment-linear
  const float*  hn2g = (const float*)(wsr + WS_HN2);

  // ---- stage x: 32 rows x 64 d -> bf16 [row][d] swizzled; accumulate xsq ----
  float xsq = 0.f;
  {
    const int p  = lane >> 1;             // d-pair 0..31
    const int r0 = (lane & 1) << 4;       // row group 0 / 16
    #pragma unroll
    for (int j = 0; j < 4; ++j) {
      f32x4 A0 = __builtin_nontemporal_load(&xb4[((2 * p) << 10) + (r0 >> 2) + j]);
      f32x4 A1 = __builtin_nontemporal_load(&xb4[((2 * p + 1) << 10) + (r0 >> 2) + j]);
      const float* a0 = (const float*)&A0;
      const float* a1 = (const float*)&A1;
      #pragma unroll
      for (int u = 0; u < 4; ++u) {
        xsq = fmaf(a0[u], a0[u], xsq);
        xsq = fmaf(a1[u], a1[u], xsq);
        int r = r0 + (j << 2) + u;
        *(unsigned*)(xw + r * 128 + ((p << 2) ^ swz(r))) = PACKTR(a0[u], a1[u]);
      }
    }
  }

  const int lrow = lane & 15;
  const int lk2  = (lane >> 4) << 4;

  // A fragments (2 row-subtiles x 2 k-steps) — same-wave lgkmcnt only
  bf16x8 af[2][2];
  #pragma unroll
  for (int s = 0; s < 2; ++s) {
    int row = (s << 4) + lrow;
    int sw = swz(row);
    af[s][0] = *(const bf16x8*)(xw + row * 128 + (lk2 ^ sw));
    af[s][1] = *(const bf16x8*)(xw + row * 128 + ((lk2 ^ 64) ^ sw));
  }

  unsigned bestu[2][4];
  #pragma unroll
  for (int s = 0; s < 2; ++s)
    #pragma unroll
    for (int r = 0; r < 4; ++r) bestu[s][r] = 0u;   // keys always > 0

  const unsigned tag0 = 511u - (unsigned)lrow;

  // ---- main loop: B + hn2 direct from L1/L2, no barriers ----
  #pragma unroll 2
  for (int ct = 0; ct < 32; ++ct) {
    const bf16x8 b0 = cbb[(ct << 7) + lane];        // kk=0 fragment
    const bf16x8 b1 = cbb[(ct << 7) + 64 + lane];   // kk=1 fragment
    const float hv = hn2g[(ct << 4) + lrow];        // 1 - c^2/2 (score shift)
    const unsigned tag = tag0 - (unsigned)(ct << 4);  // 511 - nc
    #pragma unroll
    for (int s = 0; s < 2; ++s) {
      f32x4 acc = {hv, hv, hv, hv};
      acc = __builtin_amdgcn_mfma_f32_16x16x32_bf16(af[s][0], b0, acc, 0, 0, 0);
      acc = __builtin_amdgcn_mfma_f32_16x16x32_bf16(af[s][1], b1, acc, 0, 0, 0);
      #pragma unroll
      for (int r = 0; r < 4; ++r) {
        unsigned key = (__float_as_uint(acc[r]) & 0xFFFFFE00u) | tag;
        bestu[s][r] = max(bestu[s][r], key);
      }
    }
  }

  // ---- cross-lane key-max over the 16 code columns + loss partial ----
  float vsum = 0.f;
  #pragma unroll
  for (int s = 0; s < 2; ++s) {
    #pragma unroll
    for (int r = 0; r < 4; ++r) {
      unsigned k = bestu[s][r];
      #pragma unroll
      for (int m = 1; m <= 8; m <<= 1) k = max(k, (unsigned)__shfl_xor(k, m, 64));
      if (lrow == 0) {
        idxw[(s << 4) + ((lane >> 4) << 2) + r] = (int)(511u - (k & 511u));
        vsum += __uint_as_float(k & 0xFFFFFE00u) - 1.0f;  // un-shift score
      }
    }
  }
  float lacc = xsq - 2.0f * vsum;
  #pragma unroll
  for (int m = 32; m; m >>= 1) lacc += __shfl_xor(lacc, m, 64);
  if (lane == 0) wsw[(bid << 1) + wid] = lacc;

  // ---- phase B: gather code rows -> d-major overlay -> f32x4 NCHW store ----
  {
    const int row  = lane >> 1;           // 0..31 (wave-local)
    const int half = lane & 1;            // d-half
    const int myidx = idxw[row];          // same-wave ds_read
    const float4* cbr = cb4 + (myidx << 4) + (half << 3);
    #pragma unroll
    for (int j = 0; j < 8; ++j) {
      float4 v = cbr[j];
      const int d = (half << 5) + (j << 2);
      ovl[(d + 0) * 36 + row] = v.x;
      ovl[(d + 1) * 36 + row] = v.y;
      ovl[(d + 2) * 36 + row] = v.z;
      ovl[(d + 3) * 36 + row] = v.w;
    }
  }
  {
    float* outq = out + 1 + (bimg << 18) + wrow0;
    const int r4 = (lane & 7) << 2;       // row group of 4 (16B)
    const int d0 = lane >> 3;             // base d (0..7)
    #pragma unroll
    for (int i = 0; i < 8; ++i) {
      const int d = d0 + (i << 3);
      f32x4 v = *(const f32x4*)(ovl + d * 36 + r4);       // aligned b128
      __builtin_nontemporal_store(v, (f32x4*)(outq + (d << 12) + r4));
    }
  }
}

__global__ void vq_finalize(const float* __restrict__ ws, float* __restrict__ out) {
  int t = threadIdx.x;
  __shared__ float red[4];
  float v = 0.f;
  #pragma unroll
  for (int k = 0; k < 16; ++k) v += ws[t + (k << 8)];
  #pragma unroll
  for (int m = 32; m; m >>= 1) v += __shfl_xor(v, m, 64);
  if ((t & 63) == 0) red[t >> 6] = v;
  __syncthreads();
  if (t == 0) out[0] = (red[0] + red[1] + red[2] + red[3]) * (1.25f / 8388608.0f);
}

extern "C" void kernel_launch(void* const* d_in, const int* in_sizes, int n_in,
                              void* d_out, int out_size, void* d_ws, size_t ws_size,
                              hipStream_t stream) {
  const float* x  = (const float*)d_in[0];   // 32*64*64*64 fp32 NCHW
  const float* cb = (const float*)d_in[1];   // 512*64 fp32
  float* out = (float*)d_out;                // [0]=loss, [1..]=quantized NCHW
  char*  ws  = (char*)d_ws;                  // ~84 KB used
  vq_prep<<<8, 64, 0, stream>>>(cb, ws);
  vq_main<<<2048, 128, 0, stream>>>(x, cb, ws, out, (float*)(ws + WS_RED));
  vq_finalize<<<1, 256, 0, stream>>>((float*)(ws + WS_RED), out);
}